// Round 4
// baseline (81.927 us; speedup 1.0000x reference)
//
#include <hip/hip_runtime.h>
#include <hip/hip_bf16.h>

// Disable FP contraction so every multiply/add rounds exactly like the
// numpy/JAX f32 reference (FMA fusion would change discrete voxel coords
// and flip ray_valid bits, which must be exact).
#pragma clang fp contract(off)

#define NRAYS 16384
#define NSAMP 512

typedef __attribute__((ext_vector_type(4))) float floatx4;

static __device__ __forceinline__ unsigned int expand_bits(unsigned int v) {
    v = (v * 65537u) & 4278190335u;
    v = (v * 257u)   & 251719695u;
    v = (v * 17u)    & 3272356035u;
    v = (v * 5u)     & 1227133513u;
    return v;
}

__global__ __launch_bounds__(256) void ca_kernel(
    const float* __restrict__ rays_chunk,
    const float* __restrict__ jitter,
    const int*   __restrict__ bitfield,
    float* __restrict__ out)
{
#pragma clang fp contract(off)
    const int gid  = blockIdx.x * 256 + threadIdx.x;   // one thread per sample
    const int ray  = gid >> 9;
    const int s    = gid & 511;
    const int lane = threadIdx.x & 63;   // wave = 64 consecutive samples, same ray

    // Constants: computed in f64 exactly like Python, then cast to f32.
    const float STEP  = (float)((6.0 - 0.2) / 512.0);
    const float HALFS = (float)(((6.0 - 0.2) / 512.0) / 2.0);
    const float C415  = (float)(4.0 / 15.0);
    const float C512  = (float)(5.0 / 12.0);
    const double br   = 0.0008 * 2.0 / __builtin_sqrt(12.0);
    const float BR2   = (float)(br * br);
    const float DIVB  = 1.984375f;     // BOUND - half_grid, exact in f32

    // Wave-uniform ray params (one 64B line, broadcast to all lanes).
    const float* rp = rays_chunk + ray * 6;
    const float ox = rp[0], oy = rp[1], oz = rp[2];
    const float dx = rp[3], dy = rp[4], dz = rp[5];

    // Per-ray null_diag (matches: d_sq, d_mag_sq = max((x+y)+z, 1e-10))
    const float dsx = dx * dx, dsy = dy * dy, dsz = dz * dz;
    float dms = (dsx + dsy) + dsz;
    dms = fmaxf(dms, 1e-10f);
    const float nlx = 1.0f - dsx / dms;
    const float nly = 1.0f - dsy / dms;
    const float nlz = 1.0f - dsz / dms;

    const float j = __builtin_nontemporal_load(jitter + gid);  // 256B dense/wave
    const float z = 0.2f + STEP * ((float)s + j);

    const float t0 = z - HALFS;
    const float t1 = t0 + HALFS;
    const float mu = (t0 + t1) / 2.0f;
    const float hw = (t1 - t0) / 2.0f;
    const float mu2 = mu * mu;
    const float hw2 = hw * hw;
    const float hw4 = hw2 * hw2;
    const float denom  = 3.0f * mu2 + hw2;
    const float t_mean = mu + ((2.0f * mu) * hw2) / denom;
    const float inner  = 12.0f * mu2 - hw2;
    const float denom2 = denom * denom;
    const float t_var  = hw2 / 3.0f - (C415 * (hw4 * inner)) / denom2;
    const float r_var  = BR2 * ((mu2 / 4.0f + C512 * hw2) - (C415 * hw4) / denom);

    const float px = ox + dx * t_mean;
    const float py = oy + dy * t_mean;
    const float pz = oz + dz * t_mean;

    const bool outb = (px < -2.0f) | (px > 2.0f) |
                      (py < -2.0f) | (py > 2.0f) |
                      (pz < -2.0f) | (pz > 2.0f);

    const float vx = t_var * dsx + r_var * nlx;
    const float vy = t_var * dsy + r_var * nly;
    const float vz = t_var * dsz + r_var * nlz;
    const float vmax = fmaxf(fmaxf(vx, vy), vz);

    // voxel coords — exact reference op order
    const float cxn = fminf(fmaxf(px / DIVB, -1.0f), 1.0f);
    const float cyn = fminf(fmaxf(py / DIVB, -1.0f), 1.0f);
    const float czn = fminf(fmaxf(pz / DIVB, -1.0f), 1.0f);
    const float cfx = fminf(fmaxf((cxn + 1.0f) / 2.0f * 127.0f, 0.0f), 127.0f);
    const float cfy = fminf(fmaxf((cyn + 1.0f) / 2.0f * 127.0f, 0.0f), 127.0f);
    const float cfz = fminf(fmaxf((czn + 1.0f) / 2.0f * 127.0f, 0.0f), 127.0f);
    const unsigned int ux = (unsigned int)cfx;
    const unsigned int uy = (unsigned int)cfy;
    const unsigned int uz = (unsigned int)cfz;
    unsigned int m = expand_bits(ux) | (expand_bits(uy) << 1) | (expand_bits(uz) << 2);
    if (m > 2097151u) m = 2097151u;
    const int byte = bitfield[m >> 3];          // random gather, L2-resident 1MB
    const bool alpha = ((byte >> (int)(m & 7u)) & 1) != 0;
    const bool valid = (!outb) && alpha;

    // dists: z[s+1] is in lane+1 (exact bits via shfl); lane 63 recomputes
    // it with the identical expression from jitter[gid+1] (bit-identical).
    float zn = __shfl_down(z, 1);
    if (lane == 63 && s < NSAMP - 1) {
        const float jn = __builtin_nontemporal_load(jitter + gid + 1);
        zn = 0.2f + STEP * ((float)(s + 1) + jn);
    }
    const float dist = (s < NSAMP - 1) ? (zn - z) : 0.0f;

    const size_t OFF_VALID = (size_t)NRAYS * NSAMP * 4;             // 33554432
    const size_t OFF_Z     = OFF_VALID + (size_t)NRAYS * NSAMP;     // 41943040
    const size_t OFF_D     = OFF_Z     + (size_t)NRAYS * NSAMP;     // 50331648

    floatx4 xw;
    xw[0] = px; xw[1] = py; xw[2] = pz; xw[3] = vmax;
    __builtin_nontemporal_store(xw, reinterpret_cast<floatx4*>(out + (size_t)gid * 4));
    __builtin_nontemporal_store(z,    out + OFF_Z + gid);
    __builtin_nontemporal_store(dist, out + OFF_D + gid);
    __builtin_nontemporal_store(valid ? 1.0f : 0.0f, out + OFF_VALID + gid);
}

extern "C" void kernel_launch(void* const* d_in, const int* in_sizes, int n_in,
                              void* d_out, int out_size, void* d_ws, size_t ws_size,
                              hipStream_t stream) {
    const float* rays = (const float*)d_in[0];
    const float* jit  = (const float*)d_in[1];
    const int*   bf   = (const int*)d_in[2];
    float* out = (float*)d_out;

    const int total_threads = NRAYS * NSAMP;       // 8,388,608
    dim3 grid(total_threads / 256), block(256);
    hipLaunchKernelGGL(ca_kernel, grid, block, 0, stream, rays, jit, bf, out);
}

// Round 5
// 67.255 us; speedup vs baseline: 1.2182x; 1.2182x over previous
//
#include <hip/hip_runtime.h>
#include <hip/hip_bf16.h>

// Disable FP contraction so every multiply/add rounds exactly like the
// numpy/JAX f32 reference (FMA fusion would change discrete voxel coords
// and flip ray_valid bits, which must be exact).
#pragma clang fp contract(off)

#define NRAYS 16384
#define NSAMP 512

typedef __attribute__((ext_vector_type(4))) float floatx4;

static __device__ __forceinline__ unsigned int expand_bits(unsigned int v) {
    v = (v * 65537u) & 4278190335u;
    v = (v * 257u)   & 251719695u;
    v = (v * 17u)    & 3272356035u;
    v = (v * 5u)     & 1227133513u;
    return v;
}

__global__ __launch_bounds__(256, 4) void ca_kernel(
    const float* __restrict__ rays_chunk,
    const float* __restrict__ jitter,
    const int*   __restrict__ bitfield,
    float* __restrict__ out)
{
#pragma clang fp contract(off)
    const int tid  = blockIdx.x * 256 + threadIdx.x;
    const int ray  = tid >> 6;         // one wave per ray
    const int lane = tid & 63;         // samples s = lane + 64*k, k=0..7

    // Constants: computed in f64 exactly like Python, then cast to f32.
    const float STEP  = (float)((6.0 - 0.2) / 512.0);
    const float HALFS = (float)(((6.0 - 0.2) / 512.0) / 2.0);
    const float C415  = (float)(4.0 / 15.0);
    const float C512  = (float)(5.0 / 12.0);
    const double br   = 0.0008 * 2.0 / __builtin_sqrt(12.0);
    const float BR2   = (float)(br * br);
    const float DIVB  = 1.984375f;     // BOUND - half_grid, exact in f32

    // Wave-uniform ray params.
    const float* rp = rays_chunk + ray * 6;
    const float ox = rp[0], oy = rp[1], oz = rp[2];
    const float dx = rp[3], dy = rp[4], dz = rp[5];

    // Per-ray null_diag (matches: d_sq, d_mag_sq = max((x+y)+z, 1e-10))
    const float dsx = dx * dx, dsy = dy * dy, dsz = dz * dz;
    float dms = (dsx + dsy) + dsz;
    dms = fmaxf(dms, 1e-10f);
    const float nlx = 1.0f - dsx / dms;
    const float nly = 1.0f - dsy / dms;
    const float nlz = 1.0f - dsz / dms;

    const int sbase = ray * NSAMP;

    // Coalesced jitter loads (256B dense per wave instruction).
    float jloc[8];
#pragma unroll
    for (int k = 0; k < 8; ++k)
        jloc[k] = __builtin_nontemporal_load(jitter + sbase + lane + (k << 6));

    const size_t OFF_VALID = (size_t)NRAYS * NSAMP * 4;             // 33554432
    const size_t OFF_Z     = OFF_VALID + (size_t)NRAYS * NSAMP;     // 41943040
    const size_t OFF_D     = OFF_Z     + (size_t)NRAYS * NSAMP;     // 50331648

#pragma unroll
    for (int k = 0; k < 8; ++k) {
        const int s   = lane + (k << 6);
        const int idx = sbase + s;

        const float z  = 0.2f + STEP * ((float)s + jloc[k]);
        const float t0 = z - HALFS;
        const float t1 = t0 + HALFS;
        const float mu = (t0 + t1) * 0.5f;   // bit-identical to /2
        const float hw = (t1 - t0) * 0.5f;   // bit-identical to /2
        const float mu2 = mu * mu;
        const float hw2 = hw * hw;
        const float hw4 = hw2 * hw2;
        const float denom  = 3.0f * mu2 + hw2;
        const float t_mean = mu + ((2.0f * mu) * hw2) / denom;
        const float inner  = 12.0f * mu2 - hw2;
        const float denom2 = denom * denom;
        const float t_var  = hw2 / 3.0f - (C415 * (hw4 * inner)) / denom2;
        const float r_var  = BR2 * ((mu2 * 0.25f + C512 * hw2) - (C415 * hw4) / denom);

        const float px = ox + dx * t_mean;
        const float py = oy + dy * t_mean;
        const float pz = oz + dz * t_mean;

        // |p|>2 == (p<-2)|(p>2) for finite p; abs is a free operand modifier
        const bool outb = (fabsf(px) > 2.0f) | (fabsf(py) > 2.0f) | (fabsf(pz) > 2.0f);

        const float vx = t_var * dsx + r_var * nlx;
        const float vy = t_var * dsy + r_var * nly;
        const float vz = t_var * dsz + r_var * nlz;
        const float vmax = fmaxf(fmaxf(vx, vy), vz);

        // voxel coords — exact reference op order (/2 -> *0.5 bit-identical)
        const float cxn = fminf(fmaxf(px / DIVB, -1.0f), 1.0f);
        const float cyn = fminf(fmaxf(py / DIVB, -1.0f), 1.0f);
        const float czn = fminf(fmaxf(pz / DIVB, -1.0f), 1.0f);
        const float cfx = fminf(fmaxf((cxn + 1.0f) * 0.5f * 127.0f, 0.0f), 127.0f);
        const float cfy = fminf(fmaxf((cyn + 1.0f) * 0.5f * 127.0f, 0.0f), 127.0f);
        const float cfz = fminf(fmaxf((czn + 1.0f) * 0.5f * 127.0f, 0.0f), 127.0f);
        const unsigned int ux = (unsigned int)cfx;
        const unsigned int uy = (unsigned int)cfy;
        const unsigned int uz = (unsigned int)cfz;
        unsigned int m = expand_bits(ux) | (expand_bits(uy) << 1) | (expand_bits(uz) << 2);
        if (m > 2097151u) m = 2097151u;
        const int byte = bitfield[m >> 3];          // random gather, L2-resident
        const bool alpha = ((byte >> (int)(m & 7u)) & 1) != 0;
        const bool valid = (!outb) && alpha;

        // dists: z[s+1] from lane+1 (exact bits); lane 63 recomputes with the
        // identical expression from jitter[s+1] (= jloc[k+1] of lane 0).
        const float jn = (k < 7) ? __shfl(jloc[k + 1], 0) : 0.0f;
        float zn = __shfl_down(z, 1);
        if (lane == 63) zn = 0.2f + STEP * ((float)(s + 1) + jn);
        const float dist = (s < NSAMP - 1) ? (zn - z) : 0.0f;

        floatx4 xw;
        xw[0] = px; xw[1] = py; xw[2] = pz; xw[3] = vmax;
        __builtin_nontemporal_store(xw, reinterpret_cast<floatx4*>(out + (size_t)idx * 4));
        __builtin_nontemporal_store(valid ? 1.0f : 0.0f, out + OFF_VALID + idx);
        __builtin_nontemporal_store(z,    out + OFF_Z + idx);
        __builtin_nontemporal_store(dist, out + OFF_D + idx);
    }
}

extern "C" void kernel_launch(void* const* d_in, const int* in_sizes, int n_in,
                              void* d_out, int out_size, void* d_ws, size_t ws_size,
                              hipStream_t stream) {
    const float* rays = (const float*)d_in[0];
    const float* jit  = (const float*)d_in[1];
    const int*   bf   = (const int*)d_in[2];
    float* out = (float*)d_out;

    const int total_threads = NRAYS * NSAMP / 8;   // 1,048,576
    dim3 grid(total_threads / 256), block(256);
    hipLaunchKernelGGL(ca_kernel, grid, block, 0, stream, rays, jit, bf, out);
}